// Round 7
// baseline (839.599 us; speedup 1.0000x reference)
//
#include <hip/hip_runtime.h>
#include <math.h>

// Problem constants (fixed by the reference)
#define B_N  16384
#define T_N  3
#define D_N  512
#define G_N  4
#define NE_N 4
#define H_N  512
#define E_N  256
#define GH_N 256
#define K16  16      // G*NE experts
#define TH_N 128
#define TO_N 64

typedef __attribute__((ext_vector_type(8))) short short8;
typedef __attribute__((ext_vector_type(4))) float floatx4;

__device__ __forceinline__ unsigned short f2bf(float f) {
    union { float f; unsigned u; } v; v.f = f;
    unsigned r = (v.u + 0x7fffu + ((v.u >> 16) & 1u)) >> 16;
    return (unsigned short)r;
}
__device__ __forceinline__ float bf2f(unsigned short h) {
    union { unsigned u; float f; } v; v.u = ((unsigned)h) << 16;
    return v.f;
}
__device__ __forceinline__ unsigned pack2(float lo, float hi) {
    return ((unsigned)f2bf(hi) << 16) | (unsigned)f2bf(lo);
}

typedef const __attribute__((address_space(1))) void gvoid_t;
typedef __attribute__((address_space(3))) void lvoid_t;

#if __has_builtin(__builtin_amdgcn_global_load_lds)
#define HAVE_GLL 1
__device__ __forceinline__ void load_lds16(const void* g, void* l) {
    __builtin_amdgcn_global_load_lds((gvoid_t*)g, (lvoid_t*)l, 16, 0, 0);
}
#else
#define HAVE_GLL 0
#endif

// ---------------------------------------------------------------------------
// Input cast: x -> bf16 [BC][G*D]; gin = x[:,1+t]+x[:,0] -> bf16 [BC][T*D]
// Block = 2 rows, float4 per thread.
// ---------------------------------------------------------------------------
__global__ __launch_bounds__(256) void convert_inputs(
    const float* __restrict__ x, unsigned short* __restrict__ xb,
    unsigned short* __restrict__ ginb)
{
    const long b = (long)blockIdx.x * 2 + (threadIdx.x >> 7);
    const int c = (threadIdx.x & 127) * 4;
    const float* xr = x + b * (G_N * D_N);
    unsigned short* xo = xb + b * (G_N * D_N);
    unsigned short* go = ginb + b * (T_N * D_N);
    float4 v0 = *(const float4*)&xr[c];
    { unsigned r[2] = {pack2(v0.x, v0.y), pack2(v0.z, v0.w)};
      *(uint2*)&xo[c] = *(uint2*)r; }
    #pragma unroll
    for (int g = 1; g < G_N; ++g) {
        float4 v = *(const float4*)&xr[g * D_N + c];
        unsigned r[2] = {pack2(v.x, v.y), pack2(v.z, v.w)};
        *(uint2*)&xo[g * D_N + c] = *(uint2*)r;
        unsigned s[2] = {pack2(v.x + v0.x, v.y + v0.y), pack2(v.z + v0.z, v.w + v0.w)};
        *(uint2*)&go[(g - 1) * D_N + c] = *(uint2*)s;
    }
}

// ---------------------------------------------------------------------------
// All 5 weight transposes (fp32 [Z][K][N] -> bf16 [Z][N][K]) in one dispatch.
// Segment boundaries hardcoded for this problem's shapes.
// ---------------------------------------------------------------------------
__global__ __launch_bounds__(256) void transpose_all(
    const float* __restrict__ i0, unsigned short* __restrict__ o0,   // eW1 512x512 x16
    const float* __restrict__ i1, unsigned short* __restrict__ o1,   // eW2 512x256 x16
    const float* __restrict__ i2, unsigned short* __restrict__ o2,   // gW1 512x256 x3
    const float* __restrict__ i3, unsigned short* __restrict__ o3,   // tW1 256x128 x3
    const float* __restrict__ i4, unsigned short* __restrict__ o4)   // tW2 128x64  x3
{
    __shared__ float tile[32][33];
    const int L = blockIdx.x;
    const float* in; unsigned short* out; int K, N, rem;
    if (L < 4096)      { in = i0; out = o0; K = 512; N = 512; rem = L; }
    else if (L < 6144) { in = i1; out = o1; K = 512; N = 256; rem = L - 4096; }
    else if (L < 6528) { in = i2; out = o2; K = 512; N = 256; rem = L - 6144; }
    else if (L < 6624) { in = i3; out = o3; K = 256; N = 128; rem = L - 6528; }
    else               { in = i4; out = o4; K = 128; N = 64;  rem = L - 6624; }
    const int nbx = N >> 5, nby = K >> 5;
    const int bx = rem % nbx; int t = rem / nbx;
    const int by = t % nby; const int bz = t / nby;
    const int tx = threadIdx.x, ty = threadIdx.y;      // block (32,8)
    const long zo = (long)bz * K * N;
    const int n0 = bx * 32, k0 = by * 32;
    #pragma unroll
    for (int i = 0; i < 4; ++i)
        tile[ty + 8 * i][tx] = in[zo + (long)(k0 + ty + 8 * i) * N + n0 + tx];
    __syncthreads();
    #pragma unroll
    for (int i = 0; i < 4; ++i)
        out[zo + (long)(n0 + ty + 8 * i) * K + k0 + tx] = f2bf(tile[tx][ty + 8 * i]);
}

// ---------------------------------------------------------------------------
// bf16 MFMA GEMM, B-DIRECT: C[z] = act(A[z] @ Bt[z]^T + bias[z])
//  - A staged in LDS (8 KB, XOR-swizzled, conflict-free)
//  - B fragments loaded global->VGPR (weights are L2-resident)
//  - flat grid + XCD swizzle: xcd=L&7; each XCD walks (n,z) pairs in order,
//    m strided by 8 -> one hot 128KB B-tile per XCD, 16x A-tile L2 reuse.
// Mb must be a multiple of 8.
// ---------------------------------------------------------------------------
template<int RELU>
__global__ __launch_bounds__(256, 3) void gemm_bf16(
    const unsigned short* __restrict__ A, int lda, int a_zoff,
    const unsigned short* __restrict__ Bt, int bt_zoff,
    const float* __restrict__ bias, int bias_zoff,
    unsigned short* __restrict__ C, int ldc, int c_zoff, int K,
    int Mb, int NT)
{
    __shared__ __align__(16) unsigned short As[128 * 32];
    const int tid = threadIdx.x;
    const int L = blockIdx.x;
    const int xcd = L & 7;
    const int q = L >> 3;
    const int mpx = Mb >> 3;
    const int pair = q / mpx, mloc = q % mpx;
    const int mblk = mloc * 8 + xcd;
    const int n = pair % NT;
    const int z = pair / NT;
    const long m0 = (long)mblk * 128;
    const long n0 = (long)n * 128;
    const unsigned short* Ab = A + (long)z * a_zoff + m0 * lda;
    const unsigned short* Bb = Bt + (long)z * bt_zoff + n0 * K;
    const int lane16 = tid & 15;
    const int quad = (tid & 63) >> 4;
    const int wave = tid >> 6;
    const int wm = (wave >> 1) * 64;
    const int wn = (wave & 1) * 64;
    const int srow = tid >> 2;                                 // staging row
    const int scolsw = (((tid & 3) ^ ((tid >> 3) & 3)) * 8);   // swizzled col
    const int cw8 = ((quad ^ ((lane16 >> 1) & 3)) * 8);        // frag read col

    const unsigned short* Brow = Bb + (long)(wn + lane16) * K + quad * 8;

    floatx4 acc[4][4] = {};

    for (int k0 = 0; k0 < K; k0 += 32) {
        // B fragments: global -> VGPR (L2-hot weights)
        short8 b[4];
        #pragma unroll
        for (int ni = 0; ni < 4; ++ni)
            b[ni] = *(const short8*)(Brow + (long)ni * 16 * K + k0);
        // A tile: global -> LDS
#if HAVE_GLL
        load_lds16(Ab + (long)srow * lda + k0 + scolsw, &As[tid * 8]);
        load_lds16(Ab + (long)(srow + 64) * lda + k0 + scolsw, &As[2048 + tid * 8]);
#else
        *(uint4*)&As[tid * 8] = *(const uint4*)(Ab + (long)srow * lda + k0 + scolsw);
        *(uint4*)&As[2048 + tid * 8] = *(const uint4*)(Ab + (long)(srow + 64) * lda + k0 + scolsw);
#endif
        __syncthreads();
        short8 a[4];
        #pragma unroll
        for (int mi = 0; mi < 4; ++mi)
            a[mi] = *(const short8*)&As[(wm + mi * 16 + lane16) * 32 + cw8];
        #pragma unroll
        for (int mi = 0; mi < 4; ++mi)
            #pragma unroll
            for (int ni = 0; ni < 4; ++ni)
                acc[mi][ni] = __builtin_amdgcn_mfma_f32_16x16x32_bf16(
                    a[mi], b[ni], acc[mi][ni], 0, 0, 0);
        __syncthreads();
    }

    unsigned short* Cb = C + (long)z * c_zoff + m0 * ldc + n0;
    const float* bb = bias + (long)z * bias_zoff + n0;
    #pragma unroll
    for (int mi = 0; mi < 4; ++mi) {
        #pragma unroll
        for (int ni = 0; ni < 4; ++ni) {
            const int col = wn + ni * 16 + lane16;
            const float bv = bb[col];
            #pragma unroll
            for (int r = 0; r < 4; ++r) {
                const int row = wm + mi * 16 + quad * 4 + r;
                float v = acc[mi][ni][r] + bv;
                if (RELU) v = fmaxf(v, 0.0f);
                Cb[(long)row * ldc + col] = f2bf(v);
            }
        }
    }
}

// ---------------------------------------------------------------------------
// Gate layer 2 + softmax: gw[b][t][k] = softmax_k(gh[b][t]·W2[t] + b2[t])
// ---------------------------------------------------------------------------
__global__ __launch_bounds__(256) void gate2_softmax(
    const unsigned short* __restrict__ gh, const float* __restrict__ W2,
    const float* __restrict__ b2, float* __restrict__ gw)
{
    const int t = blockIdx.y;
    const long b0 = (long)blockIdx.x * 64;
    const int tid = threadIdx.x;
    __shared__ __align__(16) unsigned short ghs[64 * 256];
    __shared__ float ls[64 * 16];
    #pragma unroll
    for (int it = 0; it < 8; ++it) {
        int seg = it * 256 + tid;
        int row = seg >> 5;
        int col = (seg & 31) * 8;
        *(uint4*)&ghs[seg * 8] =
            *(const uint4*)&gh[(b0 + row) * (T_N * GH_N) + (long)t * GH_N + col];
    }
    __syncthreads();
    const float* W2t = W2 + (long)t * GH_N * K16;
    #pragma unroll
    for (int it = 0; it < 4; ++it) {
        int o = it * 256 + tid;
        int b = o >> 4, k = o & 15;
        float acc = b2[t * K16 + k];
        #pragma unroll 8
        for (int h = 0; h < GH_N; ++h)
            acc += bf2f(ghs[b * 256 + h]) * W2t[h * K16 + k];
        ls[o] = acc;
    }
    __syncthreads();
    if (tid < 64) {
        float m = -1e30f;
        #pragma unroll
        for (int k = 0; k < 16; ++k) m = fmaxf(m, ls[tid * 16 + k]);
        float e[16], s = 0.f;
        #pragma unroll
        for (int k = 0; k < 16; ++k) { e[k] = expf(ls[tid * 16 + k] - m); s += e[k]; }
        const float inv = 1.0f / s;
        float* gwp = gw + (b0 + tid) * (T_N * K16) + (long)t * K16;
        #pragma unroll
        for (int k = 0; k < 16; ++k) gwp[k] = e[k] * inv;
    }
}

// ---------------------------------------------------------------------------
// agg: aggb[t][b][e] = bf16( sum_k gw[b][t][k] * emb[b][k*256+e] )
// ---------------------------------------------------------------------------
__global__ __launch_bounds__(256) void agg_kernel(
    const unsigned short* __restrict__ emb, const float* __restrict__ gw,
    unsigned short* __restrict__ aggb, long bc)
{
    const long b = (long)blockIdx.x * 8 + (threadIdx.x >> 5);
    const int e0 = (threadIdx.x & 31) * 8;
    const unsigned short* er = emb + b * 4096 + e0;
    const float* gwr = gw + b * 48;
    float a0[8] = {}, a1[8] = {}, a2[8] = {};
    #pragma unroll
    for (int k = 0; k < 16; ++k) {
        short8 v = *(const short8*)(er + (long)k * 256);
        const float w0 = gwr[k], w1 = gwr[16 + k], w2 = gwr[32 + k];
        #pragma unroll
        for (int j = 0; j < 8; ++j) {
            float f = bf2f((unsigned short)v[j]);
            a0[j] += w0 * f; a1[j] += w1 * f; a2[j] += w2 * f;
        }
    }
    unsigned r0[4] = {pack2(a0[0], a0[1]), pack2(a0[2], a0[3]),
                      pack2(a0[4], a0[5]), pack2(a0[6], a0[7])};
    unsigned r1[4] = {pack2(a1[0], a1[1]), pack2(a1[2], a1[3]),
                      pack2(a1[4], a1[5]), pack2(a1[6], a1[7])};
    unsigned r2[4] = {pack2(a2[0], a2[1]), pack2(a2[2], a2[3]),
                      pack2(a2[4], a2[5]), pack2(a2[6], a2[7])};
    *(uint4*)(aggb + 0L * bc * 256 + b * 256 + e0) = *(uint4*)r0;
    *(uint4*)(aggb + 1L * bc * 256 + b * 256 + e0) = *(uint4*)r1;
    *(uint4*)(aggb + 2L * bc * 256 + b * 256 + e0) = *(uint4*)r2;
}

// ---------------------------------------------------------------------------
// tower_fused (per t): th = relu(agg·W1+b1) [MFMA], out = th·W2+b2 [MFMA]
// ---------------------------------------------------------------------------
__global__ __launch_bounds__(256) void tower_fused(
    const unsigned short* __restrict__ aggb, long bc,
    const unsigned short* __restrict__ w1t, const float* __restrict__ tb1,
    const unsigned short* __restrict__ w2t, const float* __restrict__ tb2,
    float* __restrict__ out)
{
    __shared__ __align__(16) unsigned short sm[26112];   // 52224 B
    unsigned short* As  = sm;            // [128*32]   (stage 1 staging)
    unsigned short* Bs  = sm + 4096;     // [128*32]
    unsigned short* th  = sm;            // [128*136]  (reused after stage 1)
    unsigned short* w2s = sm + 17408;    // [64*136]
    const int tid = threadIdx.x;
    const int t = blockIdx.y;
    const long m0 = (long)blockIdx.x * 128;
    const unsigned short* Ab = aggb + (long)t * bc * 256 + m0 * 256;
    const unsigned short* Bb = w1t + (long)t * (TH_N * E_N);
    const int lane16 = tid & 15;
    const int quad = (tid & 63) >> 4;
    const int wave = tid >> 6;
    const int wm = (wave >> 1) * 64;
    const int wn = (wave & 1) * 64;
    const int srow = tid >> 2;
    const int scolsw = (((tid & 3) ^ ((tid >> 3) & 3)) * 8);
    const int cw8 = ((quad ^ ((lane16 >> 1) & 3)) * 8);

    // W2 tile [64][128] bf16 -> padded w2s [64][136]
    #pragma unroll
    for (int i = 0; i < 4; ++i) {
        const int seg = i * 256 + tid;
        const int row = seg >> 4, cb = (seg & 15) * 8;
        *(uint4*)&w2s[row * 136 + cb] =
            *(const uint4*)&w2t[(long)t * (TO_N * TH_N) + (long)row * 128 + cb];
    }

    floatx4 acc[4][4] = {};
    for (int k0 = 0; k0 < 256; k0 += 32) {
#if HAVE_GLL
        load_lds16(Ab + (long)srow * 256 + k0 + scolsw, &As[tid * 8]);
        load_lds16(Ab + (long)(srow + 64) * 256 + k0 + scolsw, &As[2048 + tid * 8]);
        load_lds16(Bb + (long)srow * 256 + k0 + scolsw, &Bs[tid * 8]);
        load_lds16(Bb + (long)(srow + 64) * 256 + k0 + scolsw, &Bs[2048 + tid * 8]);
#else
        *(uint4*)&As[tid * 8] = *(const uint4*)(Ab + (long)srow * 256 + k0 + scolsw);
        *(uint4*)&As[2048 + tid * 8] = *(const uint4*)(Ab + (long)(srow + 64) * 256 + k0 + scolsw);
        *(uint4*)&Bs[tid * 8] = *(const uint4*)(Bb + (long)srow * 256 + k0 + scolsw);
        *(uint4*)&Bs[2048 + tid * 8] = *(const uint4*)(Bb + (long)(srow + 64) * 256 + k0 + scolsw);
#endif
        __syncthreads();
        short8 a[4], b[4];
        #pragma unroll
        for (int mi = 0; mi < 4; ++mi)
            a[mi] = *(const short8*)&As[(wm + mi * 16 + lane16) * 32 + cw8];
        #pragma unroll
        for (int ni = 0; ni < 4; ++ni)
            b[ni] = *(const short8*)&Bs[(wn + ni * 16 + lane16) * 32 + cw8];
        #pragma unroll
        for (int mi = 0; mi < 4; ++mi)
            #pragma unroll
            for (int ni = 0; ni < 4; ++ni)
                acc[mi][ni] = __builtin_amdgcn_mfma_f32_16x16x32_bf16(
                    a[mi], b[ni], acc[mi][ni], 0, 0, 0);
        __syncthreads();
    }

    #pragma unroll
    for (int mi = 0; mi < 4; ++mi) {
        #pragma unroll
        for (int ni = 0; ni < 4; ++ni) {
            const int col = wn + ni * 16 + lane16;
            const float bv = tb1[t * TH_N + col];
            #pragma unroll
            for (int r = 0; r < 4; ++r) {
                const int row = wm + mi * 16 + quad * 4 + r;
                th[row * 136 + col] = f2bf(fmaxf(acc[mi][ni][r] + bv, 0.0f));
            }
        }
    }
    __syncthreads();

    floatx4 acc2[2][4] = {};
    #pragma unroll
    for (int kk = 0; kk < 4; ++kk) {
        short8 a2[2], b2[4];
        #pragma unroll
        for (int mi = 0; mi < 2; ++mi)
            a2[mi] = *(const short8*)&th[(wave * 32 + mi * 16 + lane16) * 136 + kk * 32 + quad * 8];
        #pragma unroll
        for (int ni = 0; ni < 4; ++ni)
            b2[ni] = *(const short8*)&w2s[(ni * 16 + lane16) * 136 + kk * 32 + quad * 8];
        #pragma unroll
        for (int mi = 0; mi < 2; ++mi)
            #pragma unroll
            for (int ni = 0; ni < 4; ++ni)
                acc2[mi][ni] = __builtin_amdgcn_mfma_f32_16x16x32_bf16(
                    a2[mi], b2[ni], acc2[mi][ni], 0, 0, 0);
    }
    #pragma unroll
    for (int mi = 0; mi < 2; ++mi) {
        #pragma unroll
        for (int ni = 0; ni < 4; ++ni) {
            const int col = ni * 16 + lane16;
            const float bv = tb2[t * TO_N + col];
            #pragma unroll
            for (int r = 0; r < 4; ++r) {
                const int row = wave * 32 + mi * 16 + quad * 4 + r;
                out[(m0 + row) * (T_N * TO_N) + t * TO_N + col] = acc2[mi][ni][r] + bv;
            }
        }
    }
}

// ---------------------------------------------------------------------------
extern "C" void kernel_launch(void* const* d_in, const int* in_sizes, int n_in,
                              void* d_out, int out_size, void* d_ws, size_t ws_size,
                              hipStream_t stream)
{
    const float* x   = (const float*)d_in[0];
    const float* eW1 = (const float*)d_in[1];
    const float* eb1 = (const float*)d_in[2];
    const float* eW2 = (const float*)d_in[3];
    const float* eb2 = (const float*)d_in[4];
    const float* gW1 = (const float*)d_in[5];
    const float* gb1 = (const float*)d_in[6];
    const float* gW2 = (const float*)d_in[7];
    const float* gb2 = (const float*)d_in[8];
    const float* tW1 = (const float*)d_in[9];
    const float* tb1 = (const float*)d_in[10];
    const float* tW2 = (const float*)d_in[11];
    const float* tb2 = (const float*)d_in[12];
    float* out = (float*)d_out;

    char* ws = (char*)d_ws;
    // Persistent weight buffers (bf16, transposed): 13,615,104 B total
    unsigned short* W1t  = (unsigned short*)(ws + 0);          // [16][512][512]
    unsigned short* W2t  = (unsigned short*)(ws + 8388608);    // [16][256][512]
    unsigned short* G1t  = (unsigned short*)(ws + 12582912);   // [3][256][512]
    unsigned short* TW1t = (unsigned short*)(ws + 13369344);   // [3][128][256]
    unsigned short* TW2t = (unsigned short*)(ws + 13565952);   // [3][64][128]
    const size_t WFIX = 13615104;

    // Adaptive chunking: BCo rows for base buffers (18,624 B/row),
    // BCh rows for the h1 intermediate (16,384 B/row). Prefer BCh >= BCo/2.
    // Min chunk 1024 so Mb = BC/128 is a multiple of 8 (XCD swizzle).
    long BCo = 0, BCh = 0;
    {
        long bestCo = 0, bestCh = 0;
        for (long co = 16384; co >= 1024; co >>= 1) {
            size_t base = WFIX + (size_t)co * 18624;
            if (base + (size_t)1024 * 16384 > ws_size) continue;
            long ch = 0;
            for (long c = co; c >= 1024; c >>= 1)
                if (base + (size_t)c * 16384 <= ws_size) { ch = c; break; }
            if (ch * 2 >= co) { bestCo = co; bestCh = ch; break; }
            if (ch > bestCh) { bestCo = co; bestCh = ch; }
        }
        BCo = bestCo; BCh = bestCh;
    }
    if (BCo == 0 || BCh == 0) return;  // workspace too small — fail cleanly

    char* p = ws + WFIX;
    unsigned short* xb   = (unsigned short*)p; p += BCo * 4096;  // [BCo][G*D]
    unsigned short* ginb = (unsigned short*)p; p += BCo * 3072;  // [BCo][T*D]
    unsigned short* embb = (unsigned short*)p; p += BCo * 8192;  // [BCo][16*E]
    unsigned short* gh   = (unsigned short*)p; p += BCo * 1536;  // [BCo][T*GH]
    float*          gw   = (float*)p;          p += BCo * 192;   // [BCo][T][16]
    unsigned short* aggb = (unsigned short*)p; p += BCo * 1536;  // [3][BCo][256]
    unsigned short* h1   = (unsigned short*)p;                   // [BCh][16*H]

    // All weight transposes in one dispatch
    transpose_all<<<6648, dim3(32, 8), 0, stream>>>(
        eW1, W1t, eW2, W2t, gW1, G1t, tW1, TW1t, tW2, TW2t);

    const long n_o = B_N / BCo;
    for (long c = 0; c < n_o; ++c) {
        const float* xc = x + c * BCo * (G_N * D_N);
        float* outc = out + c * BCo * (T_N * TO_N);

        convert_inputs<<<BCo / 2, 256, 0, stream>>>(xc, xb, ginb);
        // gate layer 1: per t: [BCo x 512] @ [512 x 256] -> relu -> gh (bf16)
        {
            const int Mb = BCo / 128;
            gemm_bf16<1><<<Mb * 2 * 3, 256, 0, stream>>>(
                ginb, 1536, 512, G1t, 131072, gb1, 256, gh, 768, 256, 512, Mb, 2);
        }
        // gate layer 2 + softmax -> gw (fp32)
        gate2_softmax<<<dim3(BCo / 64, 3), 256, 0, stream>>>(gh, gW2, gb2, gw);
        // expert layers, h1-chunked
        for (long d = 0; d < BCo / BCh; ++d) {
            const int Mb = BCh / 128;
            // L1: per g: [BCh x 512] @ [512 x 2048] -> relu -> h1
            gemm_bf16<1><<<Mb * 16 * 4, 256, 0, stream>>>(
                xb + d * BCh * 2048, 2048, 512, W1t, 1048576, eb1, 2048,
                h1, 8192, 2048, 512, Mb, 16);
            // L2: per (g,n): [BCh x 512] @ [512 x 256] -> emb
            gemm_bf16<0><<<Mb * 2 * 16, 256, 0, stream>>>(
                h1, 8192, 512, W2t, 131072, eb2, 256,
                embb + d * BCh * 4096, 4096, 256, 512, Mb, 2);
        }
        // agg -> aggb bf16 [3][BCo][256]
        agg_kernel<<<BCo / 8, 256, 0, stream>>>(embb, gw, aggb, BCo);
        // towers (MFMA, fused both layers) -> out fp32
        tower_fused<<<dim3(BCo / 128, 3), 256, 0, stream>>>(
            aggb, BCo, TW1t, tb1, TW2t, tb2, outc);
    }
}